// Round 9
// baseline (1704.859 us; speedup 1.0000x reference)
//
#include <hip/hip_runtime.h>
#include <hip/hip_bf16.h>
#include <math.h>

// Problem constants (from reference)
#define BB 64
#define TT 2048
#define VV 4096
#define EE 128
#define H2 128
#define SS 8
#define CC 2

typedef _Float16 h8 __attribute__((ext_vector_type(8)));
typedef _Float16 h4 __attribute__((ext_vector_type(4)));
typedef float f32x4 __attribute__((ext_vector_type(4)));

__device__ __forceinline__ float sigf(float x) { return 1.f / (1.f + __expf(-x)); }
__device__ __forceinline__ float tanh_fast(float x) { return 1.f - 2.f / (__expf(2.f * x) + 1.f); }

// Workgroup barrier with LDS-only drain (no vmcnt(0) — global prefetch loads
// stay in flight across steps).
__device__ __forceinline__ void lds_barrier() {
    asm volatile("s_waitcnt lgkmcnt(0)\n\ts_barrier" ::: "memory");
}

// ---------------------------------------------------------------------------
// Kernel 1: EG gate-bias table, packed per-UNIT f16x4 layout:
//   EG4[v][d][u] = {i_u, f_u, g_u, o_u} as 4 halfs (8 bytes).
// ---------------------------------------------------------------------------
__global__ __launch_bounds__(256) void eg_gemm(
    const float* __restrict__ emb,
    const float* __restrict__ Wf, const float* __restrict__ bf,
    const float* __restrict__ Wb, const float* __restrict__ bb,
    _Float16* __restrict__ EG4h)
{
    __shared__ float As[64][68];
    __shared__ float Bs[64][68];

    const int tid = threadIdx.x;
    const int tx = tid & 15, ty = tid >> 4;
    const int m0 = blockIdx.y * 64;
    const int n0 = blockIdx.x * 64;

    const float* Bsrc;
    const float* bias;
    if (n0 < 512) { Bsrc = Wf + n0 * EE; bias = bf + n0; }
    else          { Bsrc = Wb + (n0 - 512) * EE; bias = bb + (n0 - 512); }

    float acc[4][4] = {};

    for (int kc = 0; kc < 2; ++kc) {
        for (int c = tid; c < 1024; c += 256) {
            int r = c >> 4, q = c & 15;
            float4 av = *(const float4*)(emb + (size_t)(m0 + r) * EE + kc * 64 + q * 4);
            As[q * 4 + 0][r] = av.x; As[q * 4 + 1][r] = av.y;
            As[q * 4 + 2][r] = av.z; As[q * 4 + 3][r] = av.w;
            float4 bv = *(const float4*)(Bsrc + (size_t)r * EE + kc * 64 + q * 4);
            Bs[q * 4 + 0][r] = bv.x; Bs[q * 4 + 1][r] = bv.y;
            Bs[q * 4 + 2][r] = bv.z; Bs[q * 4 + 3][r] = bv.w;
        }
        __syncthreads();
        #pragma unroll 8
        for (int k = 0; k < 64; ++k) {
            float4 a4 = *(const float4*)&As[k][4 * ty];
            float4 b4 = *(const float4*)&Bs[k][4 * tx];
            float a[4] = {a4.x, a4.y, a4.z, a4.w};
            float b[4] = {b4.x, b4.y, b4.z, b4.w};
            #pragma unroll
            for (int i = 0; i < 4; ++i)
                #pragma unroll
                for (int jn = 0; jn < 4; ++jn)
                    acc[i][jn] = fmaf(a[i], b[jn], acc[i][jn]);
        }
        __syncthreads();
    }

    #pragma unroll
    for (int i = 0; i < 4; ++i) {
        int m = m0 + 4 * ty + i;                 // vocab index v
        #pragma unroll
        for (int jn = 0; jn < 4; ++jn) {
            int nn = 4 * tx + jn;
            int n = n0 + nn;                     // combined gate col
            int d = n >> 9;
            int r = n & 511;
            int gate = r >> 7;                   // 0=i,1=f,2=g,3=o
            int uu = r & 127;
            EG4h[(((size_t)m * 2 + d) * 128 + uu) * 4 + gate] =
                (_Float16)(acc[i][jn] + bias[nn]);
        }
    }
}

// ---------------------------------------------------------------------------
// Kernel 2: fused LSTM recurrence + ragged segment max-pool, MFMA matvec.
// grid = 128 blocks (b,dir). 256 threads = 4 waves, 1 wave/SIMD.
// Per step, wave w computes its 128 gate rows of G = W_hh . h via
// mfma_f32_16x16x32_f16: A = h broadcast to all 16 M rows (lane's A-frag
// = h[kt*32+quad*8+i], m-independent), B = W rows on the N axis.
// Tile j covers rows rowbase(j) = (j>>1)*128 + 32w + (j&1)*16, so lane l
// ends up holding ALL FOUR gates of units u1=32w+(l&15) and u2=u1+16 in
// its accumulators: the cell update is pure per-lane scalar math — no
// readlane, no shfl, one barrier/step (the R5/R8 readlane+dot2 wall).
// ---------------------------------------------------------------------------
__global__ __launch_bounds__(256, 1) void lstm_rec(
    const int* __restrict__ sentence, const int* __restrict__ lens,
    const float* __restrict__ Whhf, const float* __restrict__ Whhb,
    const _Float16* __restrict__ EG4h, float* __restrict__ pws)
{
    const int bid = blockIdx.x;
    const int b = bid >> 1;
    const int dir = bid & 1;            // 0 = forward, 1 = backward
    const int tid = threadIdx.x;
    const int l = tid & 63;             // lane in wave
    const int wg = tid >> 6;            // wave 0..3
    const int quad = l >> 4;            // lane quad 0..3
    const int n15 = l & 15;             // column within 16-wide tile
    const int u1 = 32 * wg + n15;       // first unit this lane owns
    const int u2 = u1 + 16;             // second unit
    const int L = lens[b];
    const int* __restrict__ srow = sentence + (size_t)b * TT;
    const float* __restrict__ Wh = (dir == 0 ? Whhf : Whhb);

    // --- prepack W_hh into MFMA B-fragments: 8 n-tiles x 4 k-tiles,
    //     lane holds B[k=quad*8+i][n=lane&15] = W[rowbase(j)+n15][kt*32+quad*8+i]
    h8 wf[8][4];
    #pragma unroll
    for (int j = 0; j < 8; ++j) {
        const int rowb = (j >> 1) * 128 + 32 * wg + (j & 1) * 16;
        const float* wr = Wh + (size_t)(rowb + n15) * H2;
        #pragma unroll
        for (int kt = 0; kt < 4; ++kt) {
            const float* q = wr + kt * 32 + quad * 8;
            float4 a = *(const float4*)q;
            float4 bq = *(const float4*)(q + 4);
            h8 f;
            f[0] = (_Float16)a.x;  f[1] = (_Float16)a.y;
            f[2] = (_Float16)a.z;  f[3] = (_Float16)a.w;
            f[4] = (_Float16)bq.x; f[5] = (_Float16)bq.y;
            f[6] = (_Float16)bq.z; f[7] = (_Float16)bq.w;
            wf[j][kt] = f;
        }
    }

    __shared__ __align__(16) _Float16 hbuf[2][128];   // double-buffered h (f16)
    if (tid < 64) ((int*)hbuf)[tid] = 0;              // zero hbuf[0]

    // per-lane EG base: element index for token v, unit u: v*256 + u
    const h4* __restrict__ eg4 = (const h4*)EG4h + (size_t)dir * 128;

    float c1 = 0.f, c2 = 0.f;
    float pm1 = -INFINITY, pm2 = -INFINITY;

    const int wseg = (L + SS - 1) >> 3;
    const bool haspad = (SS * wseg > L);
    const int padlo = L / wseg;
    int cur_seg = dir ? (SS - 1) : 0;
    int nb = dir ? (SS - 1) * wseg : wseg;
    float* __restrict__ prow = pws + ((size_t)b * 2 + dir) * SS * H2;

    // --- EG prefetch FIFO depth 3 (2 loads per slot: u1, u2) ---
    #define CL(x) (dir ? max(0, L - 1 - (x)) : min(TT - 1, (x)))
    int tk0 = srow[CL(0)], tk1 = srow[CL(1)], tk2 = srow[CL(2)];
    h4 ea0 = eg4[(size_t)tk0 * 256 + u1], eb0 = eg4[(size_t)tk0 * 256 + u2];
    h4 ea1 = eg4[(size_t)tk1 * 256 + u1], eb1 = eg4[(size_t)tk1 * 256 + u2];
    h4 ea2 = eg4[(size_t)tk2 * 256 + u1], eb2 = eg4[(size_t)tk2 * 256 + u2];
    int tok3 = srow[CL(3)];

    __syncthreads();                    // hbuf[0] init visible

    for (int t = 0; t < L; ++t) {
        const int buf = t & 1;

        // ---- A-fragments: h broadcast, 4 ds_read_b128 (same addr per quad) ----
        const _Float16* hb = &hbuf[buf][0];
        h8 af0 = *(const h8*)(hb + 0 * 32 + quad * 8);
        h8 af1 = *(const h8*)(hb + 1 * 32 + quad * 8);
        h8 af2 = *(const h8*)(hb + 2 * 32 + quad * 8);
        h8 af3 = *(const h8*)(hb + 3 * 32 + quad * 8);

        // ---- issue EG gathers for step t+3 (live across 3 barriers) ----
        h4 pa = eg4[(size_t)tok3 * 256 + u1];
        h4 pb = eg4[(size_t)tok3 * 256 + u2];
        tok3 = srow[CL(t + 4)];

        // ---- MFMA: 8 n-tiles x 4 k-chained 16x16x32 ----
        float Gv[8];
        #pragma unroll
        for (int j = 0; j < 8; ++j) {
            f32x4 acc = {0.f, 0.f, 0.f, 0.f};
            acc = __builtin_amdgcn_mfma_f32_16x16x32_f16(af0, wf[j][0], acc, 0, 0, 0);
            acc = __builtin_amdgcn_mfma_f32_16x16x32_f16(af1, wf[j][1], acc, 0, 0, 0);
            acc = __builtin_amdgcn_mfma_f32_16x16x32_f16(af2, wf[j][2], acc, 0, 0, 0);
            acc = __builtin_amdgcn_mfma_f32_16x16x32_f16(af3, wf[j][3], acc, 0, 0, 0);
            Gv[j] = acc[0];             // m-rows all equal -> reg 0 suffices
        }

        // ---- gate assembly: u1 gets tiles {0,2,4,6}, u2 gets {1,3,5,7} ----
        float gi1 = Gv[0] + (float)ea0[0];
        float gf1 = Gv[2] + (float)ea0[1];
        float gg1 = Gv[4] + (float)ea0[2];
        float go1 = Gv[6] + (float)ea0[3];
        float gi2 = Gv[1] + (float)eb0[0];
        float gf2 = Gv[3] + (float)eb0[1];
        float gg2 = Gv[5] + (float)eb0[2];
        float go2 = Gv[7] + (float)eb0[3];

        c1 = sigf(gf1) * c1 + sigf(gi1) * tanh_fast(gg1);
        float hn1 = sigf(go1) * tanh_fast(c1);
        c2 = sigf(gf2) * c2 + sigf(gi2) * tanh_fast(gg2);
        float hn2 = sigf(go2) * tanh_fast(c2);

        // ---- pooling bookkeeping (uniform branch; quad 0 writes) ----
        const int tt = dir ? (L - 1 - t) : t;
        bool bnd = dir ? (tt < nb) : (tt >= nb);
        if (bnd) {
            if (quad == 0) {
                float v1 = pm1, v2 = pm2;
                if (haspad && cur_seg >= padlo) { v1 = fmaxf(v1, 0.f); v2 = fmaxf(v2, 0.f); }
                prow[(size_t)cur_seg * H2 + u1] = v1;
                prow[(size_t)cur_seg * H2 + u2] = v2;
            }
            pm1 = -INFINITY; pm2 = -INFINITY;
            cur_seg += dir ? -1 : 1;
            nb += dir ? -wseg : wseg;
        }
        pm1 = fmaxf(pm1, hn1);
        pm2 = fmaxf(pm2, hn2);

        // ---- publish h (f16) into the other buffer; LDS-only barrier ----
        if (quad == 0) {
            hbuf[buf ^ 1][u1] = (_Float16)hn1;
            hbuf[buf ^ 1][u2] = (_Float16)hn2;
        }
        lds_barrier();

        // rotate EG FIFOs
        ea0 = ea1; ea1 = ea2; ea2 = pa;
        eb0 = eb1; eb1 = eb2; eb2 = pb;
    }
    #undef CL

    if (quad == 0) {
        float v1 = pm1, v2 = pm2;
        if (haspad && cur_seg >= padlo) { v1 = fmaxf(v1, 0.f); v2 = fmaxf(v2, 0.f); }
        prow[(size_t)cur_seg * H2 + u1] = v1;
        prow[(size_t)cur_seg * H2 + u2] = v2;
    }
}

// ---------------------------------------------------------------------------
// Kernel 3: out[b,c] = b_dense[c] + sum_k flat[b,k] * W_dense[c,k]
// ---------------------------------------------------------------------------
__global__ __launch_bounds__(256) void dense_k(
    const float* __restrict__ pws, const float* __restrict__ Wd,
    const float* __restrict__ bd, float* __restrict__ out)
{
    const int b = blockIdx.x;
    const int tid = threadIdx.x;
    float a0 = 0.f, a1 = 0.f;
    for (int k = tid; k < 2048; k += 256) {
        int h = k >> 3, s = k & 7;
        int dir = h >> 7, j = h & 127;
        float v = pws[(((size_t)b * 2 + dir) * SS + s) * H2 + j];
        a0 = fmaf(v, Wd[k], a0);
        a1 = fmaf(v, Wd[2048 + k], a1);
    }
    __shared__ float r0[256], r1[256];
    r0[tid] = a0; r1[tid] = a1;
    __syncthreads();
    for (int s = 128; s > 0; s >>= 1) {
        if (tid < s) { r0[tid] += r0[tid + s]; r1[tid] += r1[tid + s]; }
        __syncthreads();
    }
    if (tid == 0) {
        out[b * 2 + 0] = r0[0] + bd[0];
        out[b * 2 + 1] = r1[0] + bd[1];
    }
}

// ---------------------------------------------------------------------------
extern "C" void kernel_launch(void* const* d_in, const int* in_sizes, int n_in,
                              void* d_out, int out_size, void* d_ws, size_t ws_size,
                              hipStream_t stream)
{
    const int*   sentence = (const int*)d_in[0];
    const int*   lens     = (const int*)d_in[1];
    const float* emb      = (const float*)d_in[2];
    const float* Wihf     = (const float*)d_in[3];
    const float* Whhf     = (const float*)d_in[4];
    const float* bf       = (const float*)d_in[5];
    const float* Wihb     = (const float*)d_in[6];
    const float* Whhb     = (const float*)d_in[7];
    const float* bb       = (const float*)d_in[8];
    const float* Wd       = (const float*)d_in[9];
    const float* bd       = (const float*)d_in[10];
    float* out = (float*)d_out;

    _Float16* EG4h = (_Float16*)d_ws;                 // [4096][2][128][4] f16 = 8 MB
    float* pws = (float*)(EG4h + (size_t)VV * 1024);  // [64][2][8][128] fp32 = 512 KB

    eg_gemm<<<dim3(16, 64), 256, 0, stream>>>(emb, Wihf, bf, Wihb, bb, EG4h);
    lstm_rec<<<128, 256, 0, stream>>>(sentence, lens, Whhf, Whhb, EG4h, pws);
    dense_k<<<64, 256, 0, stream>>>(pws, Wd, bd, out);
}